// Round 12
// baseline (1326.162 us; speedup 1.0000x reference)
//
#include <hip/hip_runtime.h>

// 2-layer LSTM, B=512, T=1024, H=64 (tf LSTMCell, gates i,j,f,o, forget bias 1.0)
// One block (320 thr = 5 waves) per batch element. Wave g=0..3 owns gate g
// (lane = column within gate); wave 4 = serial layer-2, one step behind.
//
// Register-residency war (rounds 4-11): the backend REMATs loop-invariant
// global loads into the loop (any footprint, any waves_per_eu hint), and
// SPILLS them if remat is blocked (r11: asm-opaque loads -> 65MB scratch).
// Loophole: ds_read is NOT rematerializable (LDS is mutable shared state,
// may-alias with gs/xs writes). So: stage W1 global->LDS ONCE, ds_read each
// thread's column into registers ONCE pre-loop; the t-loop then runs pure
// VALU. launch_bounds(320,2) authorizes ~256 VGPR so the RA allocates ~100
// instead of spilling. Weights packed 24-bit (ushort hi + uchar lo of the
// fp32 bit pattern; rel err <= 2^-16) to keep LDS under 64KB/workgroup.
// h broadcast via v_readlane (register->SGPR->fmac src) - zero per-step LDS
// traffic for weights AND h. One barrier/step; gs parity double-buffered.

#define TT 1024

__device__ __forceinline__ float fsig(float x) {
    return __builtin_amdgcn_rcpf(1.f + __expf(-x));
}
__device__ __forceinline__ float ftanh(float x) {
    return 1.f - 2.f * __builtin_amdgcn_rcpf(1.f + __expf(2.f * x));
}

template <int Ctrl, int Rmask>
__device__ __forceinline__ float dpp_add(float x) {
    int t = __builtin_amdgcn_update_dpp(0, __float_as_int(x), Ctrl, Rmask, 0xf, true);
    return x + __int_as_float(t);
}
// Sum across 64 lanes; result valid in lane 63. 6 dependent VALU ops.
__device__ __forceinline__ float wave_sum64(float x) {
    x = dpp_add<0x111, 0xf>(x); // row_shr:1
    x = dpp_add<0x112, 0xf>(x); // row_shr:2
    x = dpp_add<0x114, 0xf>(x); // row_shr:4
    x = dpp_add<0x118, 0xf>(x); // row_shr:8
    x = dpp_add<0x142, 0xa>(x); // row_bcast:15
    x = dpp_add<0x143, 0xc>(x); // row_bcast:31 -> lane63 = total
    return x;
}

__device__ __forceinline__ float rl(float v, int k) {
    return __int_as_float(__builtin_amdgcn_readlane(__float_as_int(v), k));
}

__global__ __launch_bounds__(320, 2) void lstm2_kernel(
    const float* __restrict__ x,    // [B, T]
    const float* __restrict__ W1,   // [65, 256]; row0 = x, rows 1..64 = h1
    const float* __restrict__ b1,   // [256]
    const float* __restrict__ W2,   // [65, 4]; rows 0..63 = h1, row 64 = h2
    const float* __restrict__ b2,   // [4]
    float* __restrict__ y)          // [B, T]
{
    // ---- LDS: 24-bit packed W1 h-rows + misc (total ~58 KB < 64 KB) ----
    __shared__ unsigned short whi[64 * 256];      // 32 KB: fp32 bits [31:16]
    __shared__ unsigned char  wlo[64 * 256];      // 16 KB: fp32 bits [15:8]
    __shared__ __align__(16) float wxb[768];      // 3 KB: W1 row0 | b1 | W2 col-major-ish
    __shared__ __align__(16) float xs[TT];        // 4 KB
    __shared__ __align__(16) float gs[2][4][64];  // 2 KB: parity-buffered gates
    __shared__ float dbuf[2][4];

    const int tid  = threadIdx.x;
    const int b    = blockIdx.x;
    const int lane = tid & 63;
    const int g    = tid >> 6;      // 0..3 compute waves (= gate id), 4 = aux

    // ---- stage x row (coalesced float4) ----
    if (tid < 256) {
        ((float4*)xs)[tid] = ((const float4*)(x + (size_t)b * TT))[tid];
    }
    // ---- stage W1 h-rows into packed LDS (coalesced dword reads) ----
    for (int idx = tid; idx < 64 * 256; idx += 320) {
        unsigned int bits = __float_as_uint(W1[256 + idx]);
        whi[idx] = (unsigned short)(bits >> 16);
        wlo[idx] = (unsigned char)((bits >> 8) & 0xff);
    }
    // ---- stage x-row weights, biases, W2 columns ----
    if (tid < 256) {
        wxb[tid]       = W1[tid];              // x-row weight
        wxb[256 + tid] = b1[tid];              // bias
        wxb[512 + tid] = W2[tid];              // W2[0:64][0:4] flat (row-major)
    }
    __syncthreads();

    // ---- one-time LDS -> register column read (NOT rematerializable) ----
    float w[64];
    float wx = 0.f, bias = 0.f, w2g = 0.f;
    if (g < 4) {
        const int col = (g << 6) | lane;
#pragma unroll
        for (int k = 0; k < 64; ++k) {
            const int idx = (k << 8) | col;
            unsigned int bits = ((unsigned int)whi[idx] << 16) |
                                ((unsigned int)wlo[idx] << 8);
            w[k] = __uint_as_float(bits);
        }
        wx   = wxb[col];
        bias = wxb[256 + col];
        w2g  = wxb[512 + lane * 4 + g];        // W2[lane][g]
    }

    // layer-2 scalar constants (wave 4)
    const float w2h0 = W2[256], w2h1 = W2[257], w2h2 = W2[258], w2h3 = W2[259];
    const float b20 = b2[0], b21 = b2[1], b22 = b2[2], b23 = b2[3];

    float c1 = 0.f, h1 = 0.f;    // replicated state of hidden unit `lane`
    float c2 = 0.f, h2 = 0.f;    // wave-4 layer-2 state

    __syncthreads();

    float* yrow = y + (size_t)b * TT;

    for (int t = 0; t < TT; ++t) {
        const int par = t & 1;
        if (g < 4) {
            // ---- phase 1: full column dot via readlane h-broadcast ----
            const float xt = xs[t];
            float a0 = fmaf(xt, wx, bias), a1 = 0.f, a2 = 0.f, a3 = 0.f;
#pragma unroll
            for (int k = 0; k < 16; ++k) {
                a0 = fmaf(rl(h1, 4 * k + 0), w[4 * k + 0], a0);
                a1 = fmaf(rl(h1, 4 * k + 1), w[4 * k + 1], a1);
                a2 = fmaf(rl(h1, 4 * k + 2), w[4 * k + 2], a2);
                a3 = fmaf(rl(h1, 4 * k + 3), w[4 * k + 3], a3);
            }
            float p = (a0 + a1) + (a2 + a3);
            float act;
            if (g == 1)      act = ftanh(p);          // j
            else if (g == 2) act = fsig(p + 1.f);     // f (+forget bias)
            else             act = fsig(p);           // i, o
            gs[par][g][lane] = act;
        }
        __syncthreads();   // the ONLY barrier per step
        if (g < 4) {
            // ---- phase 2: replicated cell update (identical in waves 0-3) ----
            const float i_ = gs[par][0][lane], j_ = gs[par][1][lane];
            const float f_ = gs[par][2][lane], o_ = gs[par][3][lane];
            c1 = fmaf(c1, f_, i_ * j_);
            h1 = ftanh(c1) * o_;
            // layer-2 dot for gate g (off the critical path)
            float pd = wave_sum64(h1 * w2g);
            if (lane == 63) dbuf[par][g] = pd;
        } else if (t > 0 && lane == 0) {
            // ---- wave 4: layer-2 recurrence for step t-1 ----
            const int pp = par ^ 1;
            const float d0 = dbuf[pp][0], d1 = dbuf[pp][1];
            const float d2 = dbuf[pp][2], d3 = dbuf[pp][3];
            const float i2 = fsig (fmaf(h2, w2h0, d0) + b20);
            const float j2 = ftanh(fmaf(h2, w2h1, d1) + b21);
            const float f2 = fsig (fmaf(h2, w2h2, d2) + b22 + 1.f);
            const float o2 = fsig (fmaf(h2, w2h3, d3) + b23);
            c2 = fmaf(c2, f2, i2 * j2);
            h2 = ftanh(c2) * o2;
            yrow[t - 1] = h2;
        }
    }
    __syncthreads();
    if (g == 4 && lane == 0) {   // final layer-2 step (t = TT-1)
        const int pp = (TT - 1) & 1;
        const float d0 = dbuf[pp][0], d1 = dbuf[pp][1];
        const float d2 = dbuf[pp][2], d3 = dbuf[pp][3];
        const float i2 = fsig (fmaf(h2, w2h0, d0) + b20);
        const float j2 = ftanh(fmaf(h2, w2h1, d1) + b21);
        const float f2 = fsig (fmaf(h2, w2h2, d2) + b22 + 1.f);
        const float o2 = fsig (fmaf(h2, w2h3, d3) + b23);
        c2 = fmaf(c2, f2, i2 * j2);
        h2 = ftanh(c2) * o2;
        yrow[TT - 1] = h2;
    }
}

extern "C" void kernel_launch(void* const* d_in, const int* in_sizes, int n_in,
                              void* d_out, int out_size, void* d_ws, size_t ws_size,
                              hipStream_t stream) {
    const float* x  = (const float*)d_in[0];
    const float* W1 = (const float*)d_in[1];
    const float* b1 = (const float*)d_in[2];
    const float* W2 = (const float*)d_in[3];
    const float* b2 = (const float*)d_in[4];
    float* y = (float*)d_out;
    lstm2_kernel<<<512, 320, 0, stream>>>(x, W1, b1, W2, b2, y);
}